// Round 1
// baseline (2926.182 us; speedup 1.0000x reference)
//
#include <hip/hip_runtime.h>
#include <math.h>

// PointPWC multi-scale loss. B=2, scales N={8192,4096,2048,1024}.
// Inputs (B,3,N) fp32 channel-major: pc1_0..3, pc2_0..3, flow_0..3.
// Output: single fp32 scalar.

#define QPB 64      // queries (threads) per block == 1 wave
#define TILE 512    // candidate tile in LDS (float4 = 8KB)
#define NTOT 15360  // 8192+4096+2048+1024

struct Params {
  const float* pc1[4];
  const float* pc2[4];
  const float* fl[4];
  float4* cv2;   // [B][NTOT]
  float4* cvw;   // [B][NTOT]
  float* out;
};

__device__ __forceinline__ void map_block(int bid, int& s, int& b, int& i0,
                                          int& N, int& off, float& alpha) {
  int r = bid;
  if (r < 256)      { s = 0; }
  else if (r < 384) { s = 1; r -= 256; }
  else if (r < 448) { s = 2; r -= 384; }
  else              { s = 3; r -= 448; }
  int lg = 7 - s;                 // log2(chunks per batch) = log2(N/64)
  b = r >> lg;
  int chunk = r & ((1 << lg) - 1);
  i0 = chunk * QPB;
  N = 8192 >> s;
  off = 16384 - (16384 >> s);     // {0, 8192, 12288, 14336}
  alpha = 0.02f * (float)(1 << s);
}

__device__ __forceinline__ float wave_sum(float v) {
  #pragma unroll
  for (int o = 32; o; o >>= 1) v += __shfl_down(v, o, 64);
  return v;
}

template <int K>
__device__ __forceinline__ void topk_insert(float (&kd)[K], int (&ki)[K],
                                            float d, int idx) {
  if (d < kd[K - 1]) {
    #pragma unroll
    for (int m = K - 1; m >= 1; --m) {
      bool up = d < kd[m - 1];
      bool here = (!up) && (d < kd[m]);
      kd[m] = up ? kd[m - 1] : (here ? d : kd[m]);
      ki[m] = up ? ki[m - 1] : (here ? idx : ki[m]);
    }
    if (d < kd[0]) { kd[0] = d; ki[0] = idx; }
  }
}

// Brute-force KNN of one query per thread against N candidates (LDS-tiled).
// WARPCAND: candidates are p1+flow (computed during tile fill).
template <int K, bool WARPCAND>
__device__ __forceinline__ void run_knn(const float* cx, const float* cy,
                                        const float* cz, const float* fx,
                                        const float* fy, const float* fz,
                                        int N, float ax, float ay, float az,
                                        float (&kd)[K], int (&ki)[K],
                                        float4* tile) {
  #pragma unroll
  for (int m = 0; m < K; ++m) { kd[m] = 3.0e38f; ki[m] = 0; }
  for (int t0 = 0; t0 < N; t0 += TILE) {
    for (int t = threadIdx.x; t < TILE; t += QPB) {
      int j = t0 + t;
      float x = cx[j], y = cy[j], z = cz[j];
      if (WARPCAND) { x += fx[j]; y += fy[j]; z += fz[j]; }
      tile[t] = make_float4(x, y, z, 0.f);
    }
    __syncthreads();
    #pragma unroll 4
    for (int t = 0; t < TILE; ++t) {
      float4 c = tile[t];
      float dx = ax - c.x, dy = ay - c.y, dz = az - c.z;
      float d = dx * dx + dy * dy + dz * dz;
      topk_insert<K>(kd, ki, d, t0 + t);
    }
    __syncthreads();
  }
}

template <bool WARPCAND>
__device__ __forceinline__ float run_min(const float* cx, const float* cy,
                                         const float* cz, const float* fx,
                                         const float* fy, const float* fz,
                                         int N, float ax, float ay, float az,
                                         float4* tile) {
  float dmin = 3.0e38f;
  for (int t0 = 0; t0 < N; t0 += TILE) {
    for (int t = threadIdx.x; t < TILE; t += QPB) {
      int j = t0 + t;
      float x = cx[j], y = cy[j], z = cz[j];
      if (WARPCAND) { x += fx[j]; y += fy[j]; z += fz[j]; }
      tile[t] = make_float4(x, y, z, 0.f);
    }
    __syncthreads();
    #pragma unroll 4
    for (int t = 0; t < TILE; ++t) {
      float4 c = tile[t];
      float dx = ax - c.x, dy = ay - c.y, dz = az - c.z;
      float d = dx * dx + dy * dy + dz * dz;
      dmin = fminf(dmin, d);
    }
    __syncthreads();
  }
  return dmin;
}

__global__ __launch_bounds__(1) void k_zero(float* out) { out[0] = 0.f; }

// Pass A: self-KNN of p2 (k=10) -> cv2
__global__ __launch_bounds__(QPB) void k_cv2(Params P) {
  __shared__ float4 tile[TILE];
  int s, b, i0, N, off; float alpha;
  map_block(blockIdx.x, s, b, i0, N, off, alpha);
  const float* p2 = P.pc2[s] + b * 3 * N;
  int i = i0 + threadIdx.x;
  float ax = p2[i], ay = p2[N + i], az = p2[2 * N + i];
  float kd[10]; int ki[10];
  run_knn<10, false>(p2, p2 + N, p2 + 2 * N, nullptr, nullptr, nullptr,
                     N, ax, ay, az, kd, ki, tile);
  float sx = 0.f, sy = 0.f, sz = 0.f;
  #pragma unroll
  for (int m = 0; m < 10; ++m) {
    int j = ki[m];
    sx += p2[j]; sy += p2[N + j]; sz += p2[2 * N + j];
  }
  const float inv9 = 1.f / 9.f;
  P.cv2[b * NTOT + off + i] = make_float4((sx - 10.f * ax) * inv9,
                                          (sy - 10.f * ay) * inv9,
                                          (sz - 10.f * az) * inv9, 0.f);
}

// Pass B: self-KNN of p1 (k=10) -> cvw (on warp coords) + smoothness (k9)
__global__ __launch_bounds__(QPB) void k_cvw_smooth(Params P) {
  __shared__ float4 tile[TILE];
  int s, b, i0, N, off; float alpha;
  map_block(blockIdx.x, s, b, i0, N, off, alpha);
  const float* p1 = P.pc1[s] + b * 3 * N;
  const float* fl = P.fl[s] + b * 3 * N;
  int i = i0 + threadIdx.x;
  float ax = p1[i], ay = p1[N + i], az = p1[2 * N + i];
  float kd[10]; int ki[10];
  run_knn<10, false>(p1, p1 + N, p1 + 2 * N, nullptr, nullptr, nullptr,
                     N, ax, ay, az, kd, ki, tile);
  float fix = fl[i], fiy = fl[N + i], fiz = fl[2 * N + i];
  float wix = ax + fix, wiy = ay + fiy, wiz = az + fiz;
  float sx = 0.f, sy = 0.f, sz = 0.f, smooth = 0.f;
  #pragma unroll
  for (int m = 0; m < 10; ++m) {
    int j = ki[m];
    float flx = fl[j], fly = fl[N + j], flz = fl[2 * N + j];
    sx += p1[j] + flx; sy += p1[N + j] + fly; sz += p1[2 * N + j] + flz;
    if (m < 9) {   // k9 = first 9 sorted neighbors
      float gx = flx - fix, gy = fly - fiy, gz = flz - fiz;
      smooth += sqrtf(gx * gx + gy * gy + gz * gz);
    }
  }
  const float inv9 = 1.f / 9.f;
  P.cvw[b * NTOT + off + i] = make_float4((sx - 10.f * wix) * inv9,
                                          (sy - 10.f * wiy) * inv9,
                                          (sz - 10.f * wiz) * inv9, 0.f);
  float ssum = wave_sum(smooth * (1.f / 8.f));
  if (threadIdx.x == 0)
    atomicAdd(P.out, alpha * 0.5f * ssum);  // SMOOTH_W=1, mean over B=2
}

// Pass C: warp -> p2 top-5: dist1 (chamfer) + weighted cv2 interp -> curvature
__global__ __launch_bounds__(QPB) void k_cross(Params P) {
  __shared__ float4 tile[TILE];
  int s, b, i0, N, off; float alpha;
  map_block(blockIdx.x, s, b, i0, N, off, alpha);
  const float* p1 = P.pc1[s] + b * 3 * N;
  const float* fl = P.fl[s] + b * 3 * N;
  const float* p2 = P.pc2[s] + b * 3 * N;
  int i = i0 + threadIdx.x;
  float ax = p1[i] + fl[i], ay = p1[N + i] + fl[N + i],
        az = p1[2 * N + i] + fl[2 * N + i];
  float kd[5]; int ki[5];
  run_knn<5, false>(p2, p2 + N, p2 + 2 * N, nullptr, nullptr, nullptr,
                    N, ax, ay, az, kd, ki, tile);
  float dist1 = kd[0];
  float wsum = 0.f, ix = 0.f, iy = 0.f, iz = 0.f;
  #pragma unroll
  for (int m = 0; m < 5; ++m) {
    float w = 1.f / (kd[m] + 1e-8f);
    wsum += w;
    float4 cv = P.cv2[b * NTOT + off + ki[m]];
    ix += w * cv.x; iy += w * cv.y; iz += w * cv.z;
  }
  float inv = 1.f / wsum;
  ix *= inv; iy *= inv; iz *= inv;
  float4 cw = P.cvw[b * NTOT + off + i];
  float ex = ix - cw.x, ey = iy - cw.y, ez = iz - cw.z;
  float curv = ex * ex + ey * ey + ez * ez;
  float contrib = dist1 + 0.3f * curv;  // CHAMFER_W=1, CURVATURE_W=0.3
  float csum = wave_sum(contrib);
  if (threadIdx.x == 0)
    atomicAdd(P.out, alpha * 0.5f * csum);  // mean over B=2
}

// Pass D: p2 -> warp min (dist2 half of chamfer)
__global__ __launch_bounds__(QPB) void k_min(Params P) {
  __shared__ float4 tile[TILE];
  int s, b, i0, N, off; float alpha;
  map_block(blockIdx.x, s, b, i0, N, off, alpha);
  const float* p1 = P.pc1[s] + b * 3 * N;
  const float* fl = P.fl[s] + b * 3 * N;
  const float* p2 = P.pc2[s] + b * 3 * N;
  int i = i0 + threadIdx.x;
  float ax = p2[i], ay = p2[N + i], az = p2[2 * N + i];
  float dmin = run_min<true>(p1, p1 + N, p1 + 2 * N, fl, fl + N, fl + 2 * N,
                             N, ax, ay, az, tile);
  float msum = wave_sum(dmin);
  if (threadIdx.x == 0)
    atomicAdd(P.out, alpha * 0.5f * msum);
}

extern "C" void kernel_launch(void* const* d_in, const int* in_sizes, int n_in,
                              void* d_out, int out_size, void* d_ws,
                              size_t ws_size, hipStream_t stream) {
  Params P;
  for (int s = 0; s < 4; ++s) {
    P.pc1[s] = (const float*)d_in[s];
    P.pc2[s] = (const float*)d_in[4 + s];
    P.fl[s]  = (const float*)d_in[8 + s];
  }
  P.cv2 = (float4*)d_ws;
  P.cvw = (float4*)((char*)d_ws + (size_t)2 * NTOT * sizeof(float4));
  P.out = (float*)d_out;

  k_zero<<<dim3(1), dim3(1), 0, stream>>>(P.out);
  dim3 grid(480), block(QPB);
  k_cv2<<<grid, block, 0, stream>>>(P);
  k_cvw_smooth<<<grid, block, 0, stream>>>(P);
  k_cross<<<grid, block, 0, stream>>>(P);
  k_min<<<grid, block, 0, stream>>>(P);
}

// Round 2
// 712.719 us; speedup vs baseline: 4.1057x; 4.1057x over previous
//
#include <hip/hip_runtime.h>
#include <math.h>

// PointPWC multi-scale loss. B=2, scales N={8192,4096,2048,1024}.
// Inputs (B,3,N) fp32 channel-major: pc1_0..3, pc2_0..3, flow_0..3.
// Output: single fp32 scalar.
//
// R2: candidate-slice parallelism. Block = 512 threads = 64 queries x 8
// candidate slices (1 wave per slice). Each wave computes a partial top-k
// over its N/8 slice; wave 0 merges the 8 sorted partial lists from LDS and
// runs the epilogue. Raises wave count 480 -> 3840 (was 4% occupancy).

#define QPB 64      // queries per block
#define NSLICE 8    // candidate slices (waves) per block
#define BLOCK (QPB * NSLICE)
#define TILE_W 128  // candidates staged per wave per round
#define NTOT 15360  // 8192+4096+2048+1024

struct Params {
  const float* pc1[4];
  const float* pc2[4];
  const float* fl[4];
  float4* cv2;   // [B][NTOT]
  float4* cvw;   // [B][NTOT]
  float* out;
};

__device__ __forceinline__ void map_block(int bid, int& s, int& b, int& i0,
                                          int& N, int& off, float& alpha) {
  int r = bid;
  if (r < 256)      { s = 0; }
  else if (r < 384) { s = 1; r -= 256; }
  else if (r < 448) { s = 2; r -= 384; }
  else              { s = 3; r -= 448; }
  int lg = 7 - s;                 // log2(chunks per batch) = log2(N/64)
  b = r >> lg;
  int chunk = r & ((1 << lg) - 1);
  i0 = chunk * QPB;
  N = 8192 >> s;
  off = 16384 - (16384 >> s);     // {0, 8192, 12288, 14336}
  alpha = 0.02f * (float)(1 << s);
}

__device__ __forceinline__ float wave_sum(float v) {
  #pragma unroll
  for (int o = 32; o; o >>= 1) v += __shfl_down(v, o, 64);
  return v;
}

template <int K>
__device__ __forceinline__ void topk_insert(float (&kd)[K], int (&ki)[K],
                                            float d, int idx) {
  if (d < kd[K - 1]) {
    #pragma unroll
    for (int m = K - 1; m >= 1; --m) {
      bool up = d < kd[m - 1];
      bool here = (!up) && (d < kd[m]);
      kd[m] = up ? kd[m - 1] : (here ? d : kd[m]);
      ki[m] = up ? ki[m - 1] : (here ? idx : ki[m]);
    }
    if (d < kd[0]) { kd[0] = d; ki[0] = idx; }
  }
}

// Partial top-K of one query (per thread) over candidate slice [lo,hi).
// tile = this wave's private LDS staging area (TILE_W float4).
// NOTE: (hi-lo) is identical for all waves in a block -> barriers align.
template <int K, bool WARPCAND>
__device__ __forceinline__ void knn_slice(const float* cx, const float* cy,
                                          const float* cz, const float* fx,
                                          const float* fy, const float* fz,
                                          int lo, int hi, float ax, float ay,
                                          float az, float (&kd)[K],
                                          int (&ki)[K], float4* tile,
                                          int lane) {
  #pragma unroll
  for (int m = 0; m < K; ++m) { kd[m] = 3.0e38f; ki[m] = 0; }
  for (int t0 = lo; t0 < hi; t0 += TILE_W) {
    int cnt = min(TILE_W, hi - t0);
    for (int t = lane; t < cnt; t += 64) {
      int j = t0 + t;
      float x = cx[j], y = cy[j], z = cz[j];
      if (WARPCAND) { x += fx[j]; y += fy[j]; z += fz[j]; }
      tile[t] = make_float4(x, y, z, 0.f);
    }
    __syncthreads();
    #pragma unroll 2
    for (int t = 0; t < cnt; ++t) {
      float4 c = tile[t];
      float dx = ax - c.x, dy = ay - c.y, dz = az - c.z;
      float d = fmaf(dx, dx, fmaf(dy, dy, dz * dz));
      topk_insert<K>(kd, ki, d, t0 + t);
    }
    __syncthreads();
  }
}

// Merge NSLICE sorted partial lists (in LDS) into kd/ki (wave 0 only).
template <int K>
__device__ __forceinline__ void merge_lists(float (&kd)[K], int (&ki)[K],
                                            const float* md, const int* mi,
                                            int q) {
  for (int s = 1; s < NSLICE; ++s) {
    const float* pd = md + (s * QPB + q) * K;
    const int* pi = mi + (s * QPB + q) * K;
    for (int m = 0; m < K; ++m) {
      float d = pd[m];
      if (d >= kd[K - 1]) break;   // both lists sorted ascending
      topk_insert<K>(kd, ki, d, pi[m]);
    }
  }
}

__global__ __launch_bounds__(1) void k_zero(float* out) { out[0] = 0.f; }

// Pass A: self-KNN of p2 (k=10) -> cv2
__global__ __launch_bounds__(BLOCK) void k_cv2(Params P) {
  __shared__ float4 tiles[NSLICE][TILE_W];
  __shared__ float md[NSLICE * QPB * 10];
  __shared__ int mi[NSLICE * QPB * 10];
  int s, b, i0, N, off; float alpha;
  map_block(blockIdx.x, s, b, i0, N, off, alpha);
  int q = threadIdx.x & 63, wv = threadIdx.x >> 6;
  const float* p2 = P.pc2[s] + b * 3 * N;
  int i = i0 + q;
  float ax = p2[i], ay = p2[N + i], az = p2[2 * N + i];
  int sl = N / NSLICE;
  float kd[10]; int ki[10];
  knn_slice<10, false>(p2, p2 + N, p2 + 2 * N, nullptr, nullptr, nullptr,
                       wv * sl, wv * sl + sl, ax, ay, az, kd, ki,
                       tiles[wv], q);
  #pragma unroll
  for (int m = 0; m < 10; ++m) {
    md[(wv * QPB + q) * 10 + m] = kd[m];
    mi[(wv * QPB + q) * 10 + m] = ki[m];
  }
  __syncthreads();
  if (wv != 0) return;
  merge_lists<10>(kd, ki, md, mi, q);
  float sx = 0.f, sy = 0.f, sz = 0.f;
  #pragma unroll
  for (int m = 0; m < 10; ++m) {
    int j = ki[m];
    sx += p2[j]; sy += p2[N + j]; sz += p2[2 * N + j];
  }
  const float inv9 = 1.f / 9.f;
  P.cv2[b * NTOT + off + i] = make_float4((sx - 10.f * ax) * inv9,
                                          (sy - 10.f * ay) * inv9,
                                          (sz - 10.f * az) * inv9, 0.f);
}

// Pass B: self-KNN of p1 (k=10) -> cvw (on warp coords) + smoothness (k9)
__global__ __launch_bounds__(BLOCK) void k_cvw_smooth(Params P) {
  __shared__ float4 tiles[NSLICE][TILE_W];
  __shared__ float md[NSLICE * QPB * 10];
  __shared__ int mi[NSLICE * QPB * 10];
  int s, b, i0, N, off; float alpha;
  map_block(blockIdx.x, s, b, i0, N, off, alpha);
  int q = threadIdx.x & 63, wv = threadIdx.x >> 6;
  const float* p1 = P.pc1[s] + b * 3 * N;
  const float* fl = P.fl[s] + b * 3 * N;
  int i = i0 + q;
  float ax = p1[i], ay = p1[N + i], az = p1[2 * N + i];
  int sl = N / NSLICE;
  float kd[10]; int ki[10];
  knn_slice<10, false>(p1, p1 + N, p1 + 2 * N, nullptr, nullptr, nullptr,
                       wv * sl, wv * sl + sl, ax, ay, az, kd, ki,
                       tiles[wv], q);
  #pragma unroll
  for (int m = 0; m < 10; ++m) {
    md[(wv * QPB + q) * 10 + m] = kd[m];
    mi[(wv * QPB + q) * 10 + m] = ki[m];
  }
  __syncthreads();
  if (wv != 0) return;
  merge_lists<10>(kd, ki, md, mi, q);
  float fix = fl[i], fiy = fl[N + i], fiz = fl[2 * N + i];
  float wix = ax + fix, wiy = ay + fiy, wiz = az + fiz;
  float sx = 0.f, sy = 0.f, sz = 0.f, smooth = 0.f;
  #pragma unroll
  for (int m = 0; m < 10; ++m) {
    int j = ki[m];
    float flx = fl[j], fly = fl[N + j], flz = fl[2 * N + j];
    sx += p1[j] + flx; sy += p1[N + j] + fly; sz += p1[2 * N + j] + flz;
    if (m < 9) {   // k9 = first 9 sorted neighbors
      float gx = flx - fix, gy = fly - fiy, gz = flz - fiz;
      smooth += sqrtf(gx * gx + gy * gy + gz * gz);
    }
  }
  const float inv9 = 1.f / 9.f;
  P.cvw[b * NTOT + off + i] = make_float4((sx - 10.f * wix) * inv9,
                                          (sy - 10.f * wiy) * inv9,
                                          (sz - 10.f * wiz) * inv9, 0.f);
  float ssum = wave_sum(smooth * (1.f / 8.f));
  if (q == 0)
    atomicAdd(P.out, alpha * 0.5f * ssum);  // SMOOTH_W=1, mean over B=2
}

// Pass C: warp -> p2 top-5: dist1 (chamfer) + weighted cv2 interp -> curvature
__global__ __launch_bounds__(BLOCK) void k_cross(Params P) {
  __shared__ float4 tiles[NSLICE][TILE_W];
  __shared__ float md[NSLICE * QPB * 5];
  __shared__ int mi[NSLICE * QPB * 5];
  int s, b, i0, N, off; float alpha;
  map_block(blockIdx.x, s, b, i0, N, off, alpha);
  int q = threadIdx.x & 63, wv = threadIdx.x >> 6;
  const float* p1 = P.pc1[s] + b * 3 * N;
  const float* fl = P.fl[s] + b * 3 * N;
  const float* p2 = P.pc2[s] + b * 3 * N;
  int i = i0 + q;
  float ax = p1[i] + fl[i], ay = p1[N + i] + fl[N + i],
        az = p1[2 * N + i] + fl[2 * N + i];
  int sl = N / NSLICE;
  float kd[5]; int ki[5];
  knn_slice<5, false>(p2, p2 + N, p2 + 2 * N, nullptr, nullptr, nullptr,
                      wv * sl, wv * sl + sl, ax, ay, az, kd, ki,
                      tiles[wv], q);
  #pragma unroll
  for (int m = 0; m < 5; ++m) {
    md[(wv * QPB + q) * 5 + m] = kd[m];
    mi[(wv * QPB + q) * 5 + m] = ki[m];
  }
  __syncthreads();
  if (wv != 0) return;
  merge_lists<5>(kd, ki, md, mi, q);
  float dist1 = kd[0];
  float wsum = 0.f, ix = 0.f, iy = 0.f, iz = 0.f;
  #pragma unroll
  for (int m = 0; m < 5; ++m) {
    float w = 1.f / (kd[m] + 1e-8f);
    wsum += w;
    float4 cv = P.cv2[b * NTOT + off + ki[m]];
    ix += w * cv.x; iy += w * cv.y; iz += w * cv.z;
  }
  float inv = 1.f / wsum;
  ix *= inv; iy *= inv; iz *= inv;
  float4 cw = P.cvw[b * NTOT + off + i];
  float ex = ix - cw.x, ey = iy - cw.y, ez = iz - cw.z;
  float curv = ex * ex + ey * ey + ez * ez;
  float contrib = dist1 + 0.3f * curv;  // CHAMFER_W=1, CURVATURE_W=0.3
  float csum = wave_sum(contrib);
  if (q == 0)
    atomicAdd(P.out, alpha * 0.5f * csum);  // mean over B=2
}

// Pass D: p2 -> warp min (dist2 half of chamfer)
__global__ __launch_bounds__(BLOCK) void k_min(Params P) {
  __shared__ float4 tiles[NSLICE][TILE_W];
  __shared__ float pmin[NSLICE * QPB];
  int s, b, i0, N, off; float alpha;
  map_block(blockIdx.x, s, b, i0, N, off, alpha);
  int q = threadIdx.x & 63, wv = threadIdx.x >> 6;
  const float* p1 = P.pc1[s] + b * 3 * N;
  const float* fl = P.fl[s] + b * 3 * N;
  const float* p2 = P.pc2[s] + b * 3 * N;
  int i = i0 + q;
  float ax = p2[i], ay = p2[N + i], az = p2[2 * N + i];
  int sl = N / NSLICE;
  int lo = wv * sl, hi = lo + sl;
  float dmin = 3.0e38f;
  float4* tile = tiles[wv];
  for (int t0 = lo; t0 < hi; t0 += TILE_W) {
    int cnt = min(TILE_W, hi - t0);
    for (int t = q; t < cnt; t += 64) {
      int j = t0 + t;
      tile[t] = make_float4(p1[j] + fl[j], p1[N + j] + fl[N + j],
                            p1[2 * N + j] + fl[2 * N + j], 0.f);
    }
    __syncthreads();
    #pragma unroll 4
    for (int t = 0; t < cnt; ++t) {
      float4 c = tile[t];
      float dx = ax - c.x, dy = ay - c.y, dz = az - c.z;
      dmin = fminf(dmin, fmaf(dx, dx, fmaf(dy, dy, dz * dz)));
    }
    __syncthreads();
  }
  pmin[wv * QPB + q] = dmin;
  __syncthreads();
  if (wv != 0) return;
  #pragma unroll
  for (int s2 = 1; s2 < NSLICE; ++s2)
    dmin = fminf(dmin, pmin[s2 * QPB + q]);
  float msum = wave_sum(dmin);
  if (q == 0)
    atomicAdd(P.out, alpha * 0.5f * msum);
}

extern "C" void kernel_launch(void* const* d_in, const int* in_sizes, int n_in,
                              void* d_out, int out_size, void* d_ws,
                              size_t ws_size, hipStream_t stream) {
  Params P;
  for (int s = 0; s < 4; ++s) {
    P.pc1[s] = (const float*)d_in[s];
    P.pc2[s] = (const float*)d_in[4 + s];
    P.fl[s]  = (const float*)d_in[8 + s];
  }
  P.cv2 = (float4*)d_ws;
  P.cvw = (float4*)((char*)d_ws + (size_t)2 * NTOT * sizeof(float4));
  P.out = (float*)d_out;

  k_zero<<<dim3(1), dim3(1), 0, stream>>>(P.out);
  dim3 grid(480), block(BLOCK);
  k_cv2<<<grid, block, 0, stream>>>(P);
  k_cvw_smooth<<<grid, block, 0, stream>>>(P);
  k_cross<<<grid, block, 0, stream>>>(P);
  k_min<<<grid, block, 0, stream>>>(P);
}